// Round 3
// baseline (414.935 us; speedup 1.0000x reference)
//
#include <hip/hip_runtime.h>
#include <hip/hip_cooperative_groups.h>
#include <stdint.h>

namespace cg = cooperative_groups;

#define NND 4096
#define DIM 1024      // D = GC1 = GC2
#define FC1N 512

typedef __attribute__((ext_vector_type(8))) short short8;
typedef __attribute__((ext_vector_type(4))) float floatx4;
typedef unsigned short u16;
typedef unsigned int u32;

__device__ __forceinline__ u16 f2bf(float f) {
    union { float f; u32 u; } a; a.f = f;
    u32 u = a.u;
    return (u16)((u + 0x7fffu + ((u >> 16) & 1u)) >> 16);   // RNE
}
__device__ __forceinline__ float bf2f(u16 h) {
    union { u32 u; float f; } a; a.u = ((u32)h) << 16; return a.f;
}
__device__ __forceinline__ float selu_f(float x) {
    const float lam = 1.0507009873554805f;
    const float alp = 1.6732632423543772f;
    return x > 0.f ? lam * x : lam * alp * (expf(x) - 1.f);
}
__device__ __forceinline__ void async16(const u16* g, u16* l) {
    __builtin_amdgcn_global_load_lds((const __attribute__((address_space(1))) u32*)g,
                                     (__attribute__((address_space(3))) u32*)l, 16, 0, 0);
}

struct P {
    const float *x, *fw, *bw, *w1, *b1, *w2, *b2, *fcw1, *fcb1, *fcw2, *fcb2;
    u16 *Xb, *W1t, *W2t, *Yb;
    float *dinv, *pooled, *zacc, *out;
};

// ---- GEMM stage: Y(bf16)[4096][1024] = A(bf16)@W + bias, Wt given [n][k] ----
// 128x128 tile (grid=256 tiles), 8 waves 2x4 (wave 64x32), BK=64,
// double-buffered LDS (2x32KB), global_load_lds w16, XOR seg swizzle.
__device__ void gemm_stage(const u16* __restrict__ A, const u16* __restrict__ Bt,
                           const float* __restrict__ bias, u16* __restrict__ Y,
                           char* smem, int bid, int tid) {
    const int wave = tid >> 6, lane = tid & 63;
    const int q = lane >> 4, r = lane & 15;
    const int wm = wave & 1, wn = wave >> 1;          // wave tile: rows wm*64, cols wn*32
    const int Lrow = lane >> 3, Lseg = lane & 7;
    const int m0 = (bid >> 3) * 128, n0 = (bid & 7) * 128;
    const u16* src   = (wave < 4) ? A : Bt;
    const int rbase  = (wave < 4) ? m0 : n0;
    const int ldsoff = (wave < 4) ? 0 : 16384;
    const int wv4 = wave & 3;

    floatx4 acc[4][2];
    #pragma unroll
    for (int mt = 0; mt < 4; ++mt) { acc[mt][0] = (floatx4)0.f; acc[mt][1] = (floatx4)0.f; }

    auto issue = [&](int b, int kb) {
        u16* dst = (u16*)(smem + b * 32768 + ldsoff);
        #pragma unroll
        for (int c2 = 0; c2 < 4; ++c2) {
            int chunk = wv4 * 4 + c2;                  // 16 chunks of 8 rows x 64 k
            int row = chunk * 8 + Lrow;
            async16(src + (size_t)(rbase + row) * DIM + kb + ((Lseg ^ Lrow) * 8),
                    dst + chunk * 512);                // wave-uniform base + lane*16B
        }
    };

    issue(0, 0);
    #pragma unroll 1
    for (int k = 0; k < 16; ++k) {
        __syncthreads();                               // drains cur-buf loads; frees prev buf
        if (k + 1 < 16) issue((k + 1) & 1, (k + 1) * 64);   // prefetch hides behind MFMA
        const u16* As = (const u16*)(smem + (k & 1) * 32768);
        const u16* Bs = As + 8192;
        #pragma unroll
        for (int s = 0; s < 2; ++s) {                  // two K=32 sub-steps
            short8 bfr[2];
            #pragma unroll
            for (int nt = 0; nt < 2; ++nt) {
                int nl = wn * 32 + nt * 16 + r;
                bfr[nt] = *(const short8*)&Bs[nl * 64 + (((s * 4 + q) ^ (nl & 7)) * 8)];
            }
            #pragma unroll
            for (int mt = 0; mt < 4; ++mt) {
                int ml = wm * 64 + mt * 16 + r;
                short8 afr = *(const short8*)&As[ml * 64 + (((s * 4 + q) ^ (ml & 7)) * 8)];
                acc[mt][0] = __builtin_amdgcn_mfma_f32_16x16x32_bf16(afr, bfr[0], acc[mt][0], 0, 0, 0);
                acc[mt][1] = __builtin_amdgcn_mfma_f32_16x16x32_bf16(afr, bfr[1], acc[mt][1], 0, 0, 0);
            }
        }
    }
    #pragma unroll
    for (int nt = 0; nt < 2; ++nt) {
        int col = n0 + wn * 32 + nt * 16 + r;
        float bv = bias[col];
        #pragma unroll
        for (int mt = 0; mt < 4; ++mt)
            #pragma unroll
            for (int rr = 0; rr < 4; ++rr) {
                int row = m0 + wm * 64 + mt * 16 + q * 4 + rr;   // C/D: col=lane&15, row=q*4+reg
                Y[(size_t)row * DIM + col] = f2bf(acc[mt][nt][rr] + bv);
            }
    }
}

// ---- banded A-multiply + SELU; mode 0: store bf16 H; mode 1: mean-pool ------
__device__ void band_stage(const u16* __restrict__ Y, const float* __restrict__ dinv,
                           const float* __restrict__ fw, const float* __restrict__ bw,
                           u16* __restrict__ Hout, float* __restrict__ pooled,
                           int mode, int bid, int tid) {
    float wt[17];
    wt[8] = 1.f;
    #pragma unroll
    for (int j = 0; j < 8; ++j) { wt[9 + j] = fw[j]; wt[7 - j] = bw[j]; }
    const int i0 = bid * 16;                       // 256 blocks x 16 rows = 4096
    #pragma unroll 1
    for (int half = 0; half < 2; ++half) {
        const int c = half * 512 + tid;
        float sv[32];
        #pragma unroll
        for (int rl = 0; rl < 32; ++rl) {
            int gg = i0 - 8 + rl;
            sv[rl] = (gg >= 0 && gg < NND) ? dinv[gg] * bf2f(Y[(size_t)gg * DIM + c]) : 0.f;
        }
        float psum = 0.f;
        #pragma unroll
        for (int rr = 0; rr < 16; ++rr) {
            float a = 0.f;
            #pragma unroll
            for (int o = 0; o < 17; ++o) a += wt[o] * sv[rr + o];
            float v = selu_f(a * dinv[i0 + rr]);
            if (mode == 0) Hout[(size_t)(i0 + rr) * DIM + c] = f2bf(v);
            else psum += v;
        }
        if (mode) atomicAdd(&pooled[c], psum);
    }
}

__global__ void __launch_bounds__(512, 2) mega(P p) {
    cg::grid_group grid = cg::this_grid();
    const int bid = blockIdx.x, tid = threadIdx.x;
    __shared__ __align__(16) char smem[65536];

    // ---- Stage A: cvt x->bf16, transpose W1/W2, dinv, zero accumulators -----
    {
        const float4* xin = (const float4*)p.x;
        ushort4* xo = (ushort4*)p.Xb;
        int base = bid * 512 + tid;                 // 131072 threads, 1M float4
        #pragma unroll
        for (int i = 0; i < 8; ++i) {
            float4 v = xin[base + i * 131072];
            ushort4 o; o.x = f2bf(v.x); o.y = f2bf(v.y); o.z = f2bf(v.z); o.w = f2bf(v.w);
            xo[base + i * 131072] = o;
        }
        if (bid == 255) {
            for (int i = tid; i < NND; i += 512) {
                float deg = 1.f;
                #pragma unroll
                for (int j = 0; j < 8; ++j) {
                    if (i + j + 1 < NND) deg += p.fw[j];
                    if (i - j - 1 >= 0)  deg += p.bw[j];
                }
                p.dinv[i] = 1.f / sqrtf(deg);
            }
        }
        if (bid == 254) {
            for (int i = tid; i < 1536; i += 512) p.pooled[i] = 0.f;  // pooled+zacc contiguous
        }
        float (*tile)[65] = (float(*)[65])smem;
        #pragma unroll 1
        for (int j = 0; j < 2; ++j) {               // 512 transpose jobs, 2/block
            int job = bid * 2 + j;
            const float* in = (job & 256) ? p.w2 : p.w1;
            u16* outp = (job & 256) ? p.W2t : p.W1t;
            int tl = job & 255;
            int r0 = (tl >> 4) * 64, c0 = (tl & 15) * 64;
            __syncthreads();
            {
                int rr = tid >> 3, cs = tid & 7;
                const float* gsrc = in + (size_t)(r0 + rr) * DIM + c0 + cs * 8;
                float4 v0 = *(const float4*)gsrc;
                float4 v1 = *(const float4*)(gsrc + 4);
                float* tr = &tile[rr][cs * 8];
                tr[0] = v0.x; tr[1] = v0.y; tr[2] = v0.z; tr[3] = v0.w;
                tr[4] = v1.x; tr[5] = v1.y; tr[6] = v1.z; tr[7] = v1.w;
            }
            __syncthreads();
            {
                int nn = tid >> 3, ks = tid & 7;
                union { u16 h[8]; uint4 v; } o;
                #pragma unroll
                for (int kk = 0; kk < 8; ++kk) o.h[kk] = f2bf(tile[ks * 8 + kk][nn]);
                *(uint4*)(outp + (size_t)(c0 + nn) * DIM + r0 + ks * 8) = o.v;
            }
        }
    }
    grid.sync();
    gemm_stage(p.Xb, p.W1t, p.b1, p.Yb, smem, bid, tid);
    grid.sync();
    band_stage(p.Yb, p.dinv, p.fw, p.bw, p.Xb /*H1 reuses Xb*/, nullptr, 0, bid, tid);
    grid.sync();
    gemm_stage(p.Xb /*H1*/, p.W2t, p.b2, p.Yb, smem, bid, tid);
    grid.sync();
    band_stage(p.Yb, p.dinv, p.fw, p.bw, nullptr, p.pooled, 1, bid, tid);
    grid.sync();
    if (bid < 128) {                                // fc1: k-split 8 rows/block
        int kb = bid * 8;
        float s = 0.f;
        #pragma unroll
        for (int kk = 0; kk < 8; ++kk)
            s += p.pooled[kb + kk] * p.fcw1[(size_t)(kb + kk) * FC1N + tid];
        atomicAdd(&p.zacc[tid], s * (1.f / NND));
    }
    grid.sync();
    if (bid == 0) {                                 // fc2 + final reduce
        float* red = (float*)smem;
        float z = selu_f(p.zacc[tid] + p.fcb1[tid]);
        red[tid] = z * p.fcw2[tid * 2 + 0];
        red[512 + tid] = z * p.fcw2[tid * 2 + 1];
        __syncthreads();
        #pragma unroll 1
        for (int s2 = 256; s2 > 0; s2 >>= 1) {
            if (tid < s2) { red[tid] += red[tid + s2]; red[512 + tid] += red[512 + tid + s2]; }
            __syncthreads();
        }
        if (tid == 0) { p.out[0] = red[0] + p.fcb2[0]; p.out[1] = red[1] + p.fcb2[1]; }
    }
}

extern "C" void kernel_launch(void* const* d_in, const int* in_sizes, int n_in,
                              void* d_out, int out_size, void* d_ws, size_t ws_size,
                              hipStream_t stream) {
    char* ws = (char*)d_ws;
    P p;
    p.x    = (const float*)d_in[0];
    p.fw   = (const float*)d_in[1];
    p.bw   = (const float*)d_in[2];
    p.w1   = (const float*)d_in[3];
    p.b1   = (const float*)d_in[4];
    p.w2   = (const float*)d_in[5];
    p.b2   = (const float*)d_in[6];
    p.fcw1 = (const float*)d_in[7];
    p.fcb1 = (const float*)d_in[8];
    p.fcw2 = (const float*)d_in[9];
    p.fcb2 = (const float*)d_in[10];
    p.Xb   = (u16*)(ws);                            // 8 MB (reused as H1)
    p.W1t  = (u16*)(ws + (8u  << 20));              // 2 MB
    p.W2t  = (u16*)(ws + (10u << 20));              // 2 MB
    p.Yb   = (u16*)(ws + (12u << 20));              // 8 MB
    p.dinv = (float*)(ws + (20u << 20));            // 16 KB
    p.pooled = (float*)(ws + (20u << 20) + 16384);  // 1024 + 512 floats (zacc follows)
    p.zacc = p.pooled + 1024;
    p.out  = (float*)d_out;

    void* args[] = { &p };
    hipLaunchCooperativeKernel(reinterpret_cast<void*>(mega), dim3(256), dim3(512),
                               args, 0, stream);
}

// Round 4
// 146.667 us; speedup vs baseline: 2.8291x; 2.8291x over previous
//
#include <hip/hip_runtime.h>
#include <stdint.h>

#define NND 4096
#define DIM 1024      // D = GC1 = GC2
#define FC1N 512

typedef __attribute__((ext_vector_type(8))) short short8;
typedef __attribute__((ext_vector_type(4))) float floatx4;
typedef unsigned short u16;
typedef unsigned int u32;

__device__ __forceinline__ u16 f2bf(float f) {
    union { float f; u32 u; } a; a.f = f;
    u32 u = a.u;
    return (u16)((u + 0x7fffu + ((u >> 16) & 1u)) >> 16);   // RNE
}
__device__ __forceinline__ float bf2f(u16 h) {
    union { u32 u; float f; } a; a.u = ((u32)h) << 16; return a.f;
}
__device__ __forceinline__ float selu_f(float x) {
    const float lam = 1.0507009873554805f;
    const float alp = 1.6732632423543772f;
    return x > 0.f ? lam * x : lam * alp * (expf(x) - 1.f);
}
__device__ __forceinline__ void async16(const u16* g, u16* l) {
    __builtin_amdgcn_global_load_lds((const __attribute__((address_space(1))) u32*)g,
                                     (__attribute__((address_space(3))) u32*)l, 16, 0, 0);
}

// ---- prep: cvt x->bf16 (blocks 0..511), transpose W1/W2 (512..1023), zero ---
__global__ void k_prep(const float* __restrict__ x, const float* __restrict__ w1,
                       const float* __restrict__ w2, u16* __restrict__ Xb,
                       u16* __restrict__ W1t, u16* __restrict__ W2t,
                       float* __restrict__ zero_base) {
    int b = blockIdx.x, t = threadIdx.x;
    if (b < 512) {
        const float4* xin = (const float4*)x;
        ushort4* xo = (ushort4*)Xb;
        int base = b * 2048 + t;
        #pragma unroll
        for (int i = 0; i < 8; ++i) {
            float4 v = xin[base + i * 256];
            ushort4 o; o.x = f2bf(v.x); o.y = f2bf(v.y); o.z = f2bf(v.z); o.w = f2bf(v.w);
            xo[base + i * 256] = o;
        }
        if (b == 0)
            for (int i = t; i < 1537; i += 256) zero_base[i] = 0.f;  // pooled+zacc+cnt
        return;
    }
    // transpose [K][N] fp32 -> [N][K] bf16, 64x64 tiles
    int job = b - 512;
    const float* in = (job & 256) ? w2 : w1;
    u16* out = (job & 256) ? W2t : W1t;
    int tl = job & 255;
    int r0 = (tl >> 4) * 64, c0 = (tl & 15) * 64;
    __shared__ float tile[64][65];
    int cg = t & 15, rb = t >> 4;
    #pragma unroll
    for (int rr = 0; rr < 4; ++rr) {
        int row = rb + rr * 16;
        float4 v = *(const float4*)(in + (size_t)(r0 + row) * DIM + c0 + cg * 4);
        tile[row][cg * 4 + 0] = v.x; tile[row][cg * 4 + 1] = v.y;
        tile[row][cg * 4 + 2] = v.z; tile[row][cg * 4 + 3] = v.w;
    }
    __syncthreads();
    #pragma unroll
    for (int rr = 0; rr < 4; ++rr) {
        int nl = rb + rr * 16;
        int kl = cg * 4;
        ushort4 o;
        o.x = f2bf(tile[kl + 0][nl]); o.y = f2bf(tile[kl + 1][nl]);
        o.z = f2bf(tile[kl + 2][nl]); o.w = f2bf(tile[kl + 3][nl]);
        *(ushort4*)(out + (size_t)(c0 + nl) * DIM + r0 + kl) = o;
    }
}

// ---- fused GEMM + band-stencil + SELU --------------------------------------
// Block: output rows m0..m0+127, cols n0..n0+63. Internal Y rows m0-16..m0+143
// (160 rows; +-8 halo used, edges clamped and zeroed via sdinv=0).
// 4 waves 2Mx2N, wave tile 80x32. BK=64 dbuf + global_load_lds w16 + XOR swizzle.
// mode 0: write H bf16. mode 1: column mean-pool partials via atomicAdd.
__launch_bounds__(256, 2)
__global__ void k_gemmband(const u16* __restrict__ A, const u16* __restrict__ Bt,
                           const float* __restrict__ bias,
                           const float* __restrict__ fw, const float* __restrict__ bw,
                           u16* __restrict__ H, float* __restrict__ pooled, int mode) {
    __shared__ __align__(16) u16 stage[2][14336];   // per buf: A 160x64 u16 | B 64x64 u16
    __shared__ float sdinv_s[160];
    __shared__ float wt_s[17];
    __shared__ float pl[4][64];

    const int m0 = blockIdx.x * 128, n0 = blockIdx.y * 64;
    const int t = threadIdx.x, wave = t >> 6, lane = t & 63;
    const int q = lane >> 4, r = lane & 15;
    const int wm = wave & 1, wn = wave >> 1;
    const int Lrow = lane >> 3, Lseg = lane & 7;

    if (t < 160) {                                  // sdinv for internal rows
        int g = m0 - 16 + t;
        float s = 0.f;
        if (g >= 0 && g < NND) {
            float deg = 1.f;
            #pragma unroll
            for (int j = 0; j < 8; ++j) {
                if (g + j + 1 < NND) deg += fw[j];
                if (g - j - 1 >= 0)  deg += bw[j];
            }
            s = 1.f / sqrtf(deg);
        }
        sdinv_s[t] = s;
    } else if (t >= 192 && t < 209) {
        int o = t - 200;                            // -8..8
        wt_s[t - 192] = (o == 0) ? 1.f : (o > 0 ? fw[o - 1] : bw[-o - 1]);
    }

    floatx4 acc[5][2];
    #pragma unroll
    for (int mt = 0; mt < 5; ++mt) { acc[mt][0] = (floatx4)0.f; acc[mt][1] = (floatx4)0.f; }

    auto issue = [&](int buf, int kb) {
        #pragma unroll
        for (int i = 0; i < 7; ++i) {               // 28 chunks: 20 A + 8 B
            int c = wave * 7 + i;
            u16* dst = &stage[buf][c * 512];        // wave-uniform base + lane*16B
            const u16* src;
            if (c < 20) {
                int row = c * 8 + Lrow;             // internal A row 0..159
                int g = m0 - 16 + row;
                g = g < 0 ? 0 : (g > NND - 1 ? NND - 1 : g);   // clamp; zeroed by sdinv
                src = A + (size_t)g * DIM + kb + ((Lseg ^ Lrow) * 8);
            } else {
                int row = (c - 20) * 8 + Lrow;      // B row 0..63
                src = Bt + (size_t)(n0 + row) * DIM + kb + ((Lseg ^ Lrow) * 8);
            }
            async16(src, dst);
        }
    };

    issue(0, 0);
    #pragma unroll 1
    for (int k = 0; k < 16; ++k) {
        __syncthreads();                            // drains cur-buf loads
        if (k < 15) issue((k + 1) & 1, (k + 1) * 64);
        const u16* As = &stage[k & 1][0];
        const u16* Bs = &stage[k & 1][10240];
        #pragma unroll
        for (int s = 0; s < 2; ++s) {
            int j0 = s * 4 + q;
            short8 bfr[2];
            #pragma unroll
            for (int nt = 0; nt < 2; ++nt) {
                int nl = wn * 32 + nt * 16 + r;
                bfr[nt] = *(const short8*)&Bs[nl * 64 + ((j0 ^ (nl & 7)) * 8)];
            }
            #pragma unroll
            for (int mt = 0; mt < 5; ++mt) {
                int ml = wm * 80 + mt * 16 + r;
                short8 afr = *(const short8*)&As[ml * 64 + ((j0 ^ (ml & 7)) * 8)];
                acc[mt][0] = __builtin_amdgcn_mfma_f32_16x16x32_bf16(afr, bfr[0], acc[mt][0], 0, 0, 0);
                acc[mt][1] = __builtin_amdgcn_mfma_f32_16x16x32_bf16(afr, bfr[1], acc[mt][1], 0, 0, 0);
            }
        }
    }
    __syncthreads();                                // K-loop done; reuse stage as Yt
    float (*Yt)[65] = (float(*)[65])&stage[0][0];   // 160x65 fp32 = 41.6 KB <= 57.3 KB
    #pragma unroll
    for (int nt = 0; nt < 2; ++nt) {
        int col = wn * 32 + nt * 16 + r;
        float bv = bias[n0 + col];
        #pragma unroll
        for (int mt = 0; mt < 5; ++mt)
            #pragma unroll
            for (int rr = 0; rr < 4; ++rr)          // C/D: col=lane&15, row=q*4+reg
                Yt[wm * 80 + mt * 16 + q * 4 + rr][col] = acc[mt][nt][rr] + bv;
    }
    __syncthreads();

    // band stencil: each thread 32 output rows x 1 col; rotating 17-tap window
    int col = t & 63;
    int r0w = (t >> 6) * 32;
    float w[17];
    #pragma unroll
    for (int o = 0; o < 17; ++o) w[o] = wt_s[o];
    float win[17];
    #pragma unroll
    for (int j = 0; j < 16; ++j) {
        int T = r0w + 8 + j;
        win[j] = sdinv_s[T] * Yt[T][col];
    }
    float psum = 0.f;
    #pragma unroll
    for (int rr = 0; rr < 32; ++rr) {
        int T = r0w + 24 + rr;
        win[(rr + 16) % 17] = sdinv_s[T] * Yt[T][col];
        float a = 0.f;
        #pragma unroll
        for (int o = 0; o < 17; ++o) a += w[o] * win[(rr + o) % 17];
        float v = selu_f(a * sdinv_s[r0w + 16 + rr]);
        if (mode == 0) H[(size_t)(m0 + r0w + rr) * DIM + n0 + col] = f2bf(v);
        else psum += v;
    }
    if (mode) {
        pl[wave][col] = psum;
        __syncthreads();
        if (t < 64)
            atomicAdd(&pooled[n0 + t], pl[0][t] + pl[1][t] + pl[2][t] + pl[3][t]);
    }
}

// ---- FC head: 16-block k-split fc1; last block runs fc2 ---------------------
__global__ void k_fc(const float* __restrict__ pooled, const float* __restrict__ fcw1,
                     const float* __restrict__ fcb1, const float* __restrict__ fcw2,
                     const float* __restrict__ fcb2, float* __restrict__ zacc,
                     u32* __restrict__ cnt, float* __restrict__ out) {
    __shared__ float red[1024];
    __shared__ int lastf;
    int o = threadIdx.x, b = blockIdx.x;
    int kb = b * 64;
    float s = 0.f;
    #pragma unroll 4
    for (int kk = 0; kk < 64; ++kk)
        s += pooled[kb + kk] * fcw1[(size_t)(kb + kk) * FC1N + o];
    atomicAdd(&zacc[o], s * (1.f / NND));
    __threadfence();
    __syncthreads();
    if (o == 0) lastf = (atomicAdd(cnt, 1u) == 15u);
    __syncthreads();
    if (!lastf) return;
    __threadfence();
    float zv = atomicAdd(&zacc[o], 0.f);            // L2 read (bypass stale L1)
    float z = selu_f(zv + fcb1[o]);
    red[o] = z * fcw2[o * 2 + 0];
    red[512 + o] = z * fcw2[o * 2 + 1];
    __syncthreads();
    #pragma unroll 1
    for (int s2 = 256; s2 > 0; s2 >>= 1) {
        if (o < s2) { red[o] += red[o + s2]; red[512 + o] += red[512 + o + s2]; }
        __syncthreads();
    }
    if (o == 0) { out[0] = red[0] + fcb2[0]; out[1] = red[1] + fcb2[1]; }
}

extern "C" void kernel_launch(void* const* d_in, const int* in_sizes, int n_in,
                              void* d_out, int out_size, void* d_ws, size_t ws_size,
                              hipStream_t stream) {
    const float* x     = (const float*)d_in[0];
    const float* fw    = (const float*)d_in[1];
    const float* bw    = (const float*)d_in[2];
    const float* gc_w1 = (const float*)d_in[3];
    const float* gc_b1 = (const float*)d_in[4];
    const float* gc_w2 = (const float*)d_in[5];
    const float* gc_b2 = (const float*)d_in[6];
    const float* fc_w1 = (const float*)d_in[7];
    const float* fc_b1 = (const float*)d_in[8];
    const float* fc_w2 = (const float*)d_in[9];
    const float* fc_b2 = (const float*)d_in[10];
    float* out = (float*)d_out;

    char* ws = (char*)d_ws;
    u16*   Xb     = (u16*)(ws);                       // 8 MB
    u16*   H1     = (u16*)(ws + (8u  << 20));         // 8 MB
    u16*   W1t    = (u16*)(ws + (16u << 20));         // 2 MB
    u16*   W2t    = (u16*)(ws + (18u << 20));         // 2 MB
    float* pooled = (float*)(ws + (20u << 20));       // 1024 f
    float* zacc   = pooled + 1024;                    // 512 f
    u32*   cnt    = (u32*)(zacc + 512);               // 1 u32 (zeroed with pooled)

    k_prep<<<1024, 256, 0, stream>>>(x, gc_w1, gc_w2, Xb, W1t, W2t, pooled);
    k_gemmband<<<dim3(32, 16), 256, 0, stream>>>(Xb, W1t, gc_b1, fw, bw, H1, nullptr, 0);
    k_gemmband<<<dim3(32, 16), 256, 0, stream>>>(H1, W2t, gc_b2, fw, bw, nullptr, pooled, 1);
    k_fc<<<16, 512, 0, stream>>>(pooled, fc_w1, fc_b1, fc_w2, fc_b2, zacc, cnt, out);
}

// Round 5
// 143.822 us; speedup vs baseline: 2.8851x; 1.0198x over previous
//
#include <hip/hip_runtime.h>
#include <stdint.h>

#define NND 4096
#define DIM 1024      // D = GC1 = GC2
#define FC1N 512

typedef __attribute__((ext_vector_type(8))) short short8;
typedef __attribute__((ext_vector_type(4))) float floatx4;
typedef unsigned short u16;
typedef unsigned int u32;

__device__ __forceinline__ u16 f2bf(float f) {
    union { float f; u32 u; } a; a.f = f;
    u32 u = a.u;
    return (u16)((u + 0x7fffu + ((u >> 16) & 1u)) >> 16);   // RNE
}
__device__ __forceinline__ float bf2f(u16 h) {
    union { u32 u; float f; } a; a.u = ((u32)h) << 16; return a.f;
}
__device__ __forceinline__ float selu_f(float x) {
    const float lam = 1.0507009873554805f;
    const float alp = 1.6732632423543772f;
    return x > 0.f ? lam * x : lam * alp * (expf(x) - 1.f);
}
__device__ __forceinline__ void async16(const u16* g, u16* l) {
    __builtin_amdgcn_global_load_lds((const __attribute__((address_space(1))) u32*)g,
                                     (__attribute__((address_space(3))) u32*)l, 16, 0, 0);
}

// ---- prep: cvt x->bf16 (blocks 0..511), transpose W1/W2 (512..1023), zero ---
__global__ void k_prep(const float* __restrict__ x, const float* __restrict__ w1,
                       const float* __restrict__ w2, u16* __restrict__ Xb,
                       u16* __restrict__ W1t, u16* __restrict__ W2t,
                       float* __restrict__ zero_base) {
    int b = blockIdx.x, t = threadIdx.x;
    if (b < 512) {
        const float4* xin = (const float4*)x;
        ushort4* xo = (ushort4*)Xb;
        int base = b * 2048 + t;
        #pragma unroll
        for (int i = 0; i < 8; ++i) {
            float4 v = xin[base + i * 256];
            ushort4 o; o.x = f2bf(v.x); o.y = f2bf(v.y); o.z = f2bf(v.z); o.w = f2bf(v.w);
            xo[base + i * 256] = o;
        }
        if (b == 0)
            for (int i = t; i < 1537; i += 256) zero_base[i] = 0.f;  // pooled+zacc+cnt
        return;
    }
    // transpose [K][N] fp32 -> [N][K] bf16, 64x64 tiles
    int job = b - 512;
    const float* in = (job & 256) ? w2 : w1;
    u16* out = (job & 256) ? W2t : W1t;
    int tl = job & 255;
    int r0 = (tl >> 4) * 64, c0 = (tl & 15) * 64;
    __shared__ float tile[64][65];
    int cg = t & 15, rb = t >> 4;
    #pragma unroll
    for (int rr = 0; rr < 4; ++rr) {
        int row = rb + rr * 16;
        float4 v = *(const float4*)(in + (size_t)(r0 + row) * DIM + c0 + cg * 4);
        tile[row][cg * 4 + 0] = v.x; tile[row][cg * 4 + 1] = v.y;
        tile[row][cg * 4 + 2] = v.z; tile[row][cg * 4 + 3] = v.w;
    }
    __syncthreads();
    #pragma unroll
    for (int rr = 0; rr < 4; ++rr) {
        int nl = rb + rr * 16;
        int kl = cg * 4;
        ushort4 o;
        o.x = f2bf(tile[kl + 0][nl]); o.y = f2bf(tile[kl + 1][nl]);
        o.z = f2bf(tile[kl + 2][nl]); o.w = f2bf(tile[kl + 3][nl]);
        *(ushort4*)(out + (size_t)(c0 + nl) * DIM + r0 + kl) = o;
    }
}

// ---- fused GEMM + band-stencil + SELU --------------------------------------
// Block: output rows m0..m0+63, cols n0..n0+63. Internal rows m0-16..m0+79
// (96 rows; +-8 halo used, edge rows clamped and zeroed via sdinv=0).
// 4 waves 2Mx2N (wave tile 48x32). BK=64 single-buffer, global_load_lds w16,
// XOR seg swizzle. Grid 64x16 = 1024 blocks = 4 blocks/CU = 16 waves/CU.
// mode 0: write H bf16. mode 1: column mean-pool partials via atomicAdd.
__launch_bounds__(256, 4)
__global__ void k_gemmband(const u16* __restrict__ A, const u16* __restrict__ Bt,
                           const float* __restrict__ bias,
                           const float* __restrict__ fw, const float* __restrict__ bw,
                           u16* __restrict__ H, float* __restrict__ pooled, int mode) {
    __shared__ __align__(16) u16 stage[10240];      // A 96x64 (6144) | B 64x64 (4096)
    __shared__ float sdinv_s[96];
    __shared__ float wt_s[17];
    __shared__ float pl[4][64];

    const int m0 = blockIdx.x * 64, n0 = blockIdx.y * 64;
    const int t = threadIdx.x, wave = t >> 6, lane = t & 63;
    const int q = lane >> 4, r = lane & 15;
    const int wm = wave & 1, wn = wave >> 1;
    const int Lrow = lane >> 3, Lseg = lane & 7;

    if (t < 96) {                                   // sdinv for internal rows
        int g = m0 - 16 + t;
        float s = 0.f;
        if (g >= 0 && g < NND) {
            float deg = 1.f;
            #pragma unroll
            for (int j = 0; j < 8; ++j) {
                if (g + j + 1 < NND) deg += fw[j];
                if (g - j - 1 >= 0)  deg += bw[j];
            }
            s = 1.f / sqrtf(deg);
        }
        sdinv_s[t] = s;
    } else if (t >= 128 && t < 145) {
        int o = t - 136;                            // -8..8
        wt_s[t - 128] = (o == 0) ? 1.f : (o > 0 ? fw[o - 1] : bw[-o - 1]);
    }

    floatx4 acc[3][2];
    #pragma unroll
    for (int mt = 0; mt < 3; ++mt) { acc[mt][0] = (floatx4)0.f; acc[mt][1] = (floatx4)0.f; }

    #pragma unroll 1
    for (int k = 0; k < 16; ++k) {
        int kb = k * 64;
        #pragma unroll
        for (int i = 0; i < 5; ++i) {               // 20 chunks: 12 A + 8 B, 5/wave
            int c = wave * 5 + i;
            u16* dst = &stage[c * 512];             // wave-uniform base + lane*16B
            const u16* src;
            if (c < 12) {
                int row = c * 8 + Lrow;             // internal A row 0..95
                int g = m0 - 16 + row;
                g = g < 0 ? 0 : (g > NND - 1 ? NND - 1 : g);  // clamp; zeroed by sdinv
                src = A + (size_t)g * DIM + kb + ((Lseg ^ Lrow) * 8);
            } else {
                int row = (c - 12) * 8 + Lrow;      // B row 0..63
                src = Bt + (size_t)(n0 + row) * DIM + kb + ((Lseg ^ Lrow) * 8);
            }
            async16(src, dst);
        }
        __syncthreads();                            // drains staging loads
        const u16* As = &stage[0];
        const u16* Bs = &stage[6144];
        #pragma unroll
        for (int s = 0; s < 2; ++s) {               // two K=32 sub-steps
            int j0 = s * 4 + q;
            short8 bfr[2];
            #pragma unroll
            for (int nt = 0; nt < 2; ++nt) {
                int nl = wn * 32 + nt * 16 + r;
                bfr[nt] = *(const short8*)&Bs[nl * 64 + ((j0 ^ (nl & 7)) * 8)];
            }
            #pragma unroll
            for (int mt = 0; mt < 3; ++mt) {
                int ml = wm * 48 + mt * 16 + r;
                short8 afr = *(const short8*)&As[ml * 64 + ((j0 ^ (ml & 7)) * 8)];
                acc[mt][0] = __builtin_amdgcn_mfma_f32_16x16x32_bf16(afr, bfr[0], acc[mt][0], 0, 0, 0);
                acc[mt][1] = __builtin_amdgcn_mfma_f32_16x16x32_bf16(afr, bfr[1], acc[mt][1], 0, 0, 0);
            }
        }
        __syncthreads();                            // ds_reads done before re-stage
    }
    // epilogue: Y tile (bf16) aliased over stage
    u16 (*Yt)[66] = (u16(*)[66])&stage[0];          // 96x66 u16 = 12.4 KB <= 20 KB
    #pragma unroll
    for (int nt = 0; nt < 2; ++nt) {
        int col = wn * 32 + nt * 16 + r;
        float bv = bias[n0 + col];
        #pragma unroll
        for (int mt = 0; mt < 3; ++mt)
            #pragma unroll
            for (int rr = 0; rr < 4; ++rr)          // C/D: col=lane&15, row=q*4+reg
                Yt[wm * 48 + mt * 16 + q * 4 + rr][col] = f2bf(acc[mt][nt][rr] + bv);
    }
    __syncthreads();

    // band stencil: each thread 16 output rows x 1 col; rotating 17-tap window
    int col = t & 63;
    int r0w = (t >> 6) * 16;
    float w[17];
    #pragma unroll
    for (int o = 0; o < 17; ++o) w[o] = wt_s[o];
    float win[17];
    #pragma unroll
    for (int j = 0; j < 16; ++j) {
        int T = r0w + 8 + j;
        win[j] = sdinv_s[T] * bf2f(Yt[T][col]);
    }
    float psum = 0.f;
    #pragma unroll
    for (int rr = 0; rr < 16; ++rr) {
        int T = r0w + 24 + rr;
        win[(rr + 16) % 17] = sdinv_s[T] * bf2f(Yt[T][col]);
        float a = 0.f;
        #pragma unroll
        for (int o = 0; o < 17; ++o) a += w[o] * win[(rr + o) % 17];
        float v = selu_f(a * sdinv_s[r0w + 16 + rr]);
        if (mode == 0) H[(size_t)(m0 + r0w + rr) * DIM + n0 + col] = f2bf(v);
        else psum += v;
    }
    if (mode) {
        pl[wave][col] = psum;
        __syncthreads();
        if (t < 64)
            atomicAdd(&pooled[n0 + t], pl[0][t] + pl[1][t] + pl[2][t] + pl[3][t]);
    }
}

// ---- FC head: 16-block k-split fc1; last block runs fc2 ---------------------
__global__ void k_fc(const float* __restrict__ pooled, const float* __restrict__ fcw1,
                     const float* __restrict__ fcb1, const float* __restrict__ fcw2,
                     const float* __restrict__ fcb2, float* __restrict__ zacc,
                     u32* __restrict__ cnt, float* __restrict__ out) {
    __shared__ float red[1024];
    __shared__ int lastf;
    int o = threadIdx.x, b = blockIdx.x;
    int kb = b * 64;
    float s = 0.f;
    #pragma unroll 4
    for (int kk = 0; kk < 64; ++kk)
        s += pooled[kb + kk] * fcw1[(size_t)(kb + kk) * FC1N + o];
    atomicAdd(&zacc[o], s * (1.f / NND));
    __threadfence();
    __syncthreads();
    if (o == 0) lastf = (atomicAdd(cnt, 1u) == 15u);
    __syncthreads();
    if (!lastf) return;
    __threadfence();
    float zv = atomicAdd(&zacc[o], 0.f);            // L2 read (bypass stale L1)
    float z = selu_f(zv + fcb1[o]);
    red[o] = z * fcw2[o * 2 + 0];
    red[512 + o] = z * fcw2[o * 2 + 1];
    __syncthreads();
    #pragma unroll 1
    for (int s2 = 256; s2 > 0; s2 >>= 1) {
        if (o < s2) { red[o] += red[o + s2]; red[512 + o] += red[512 + o + s2]; }
        __syncthreads();
    }
    if (o == 0) { out[0] = red[0] + fcb2[0]; out[1] = red[1] + fcb2[1]; }
}

extern "C" void kernel_launch(void* const* d_in, const int* in_sizes, int n_in,
                              void* d_out, int out_size, void* d_ws, size_t ws_size,
                              hipStream_t stream) {
    const float* x     = (const float*)d_in[0];
    const float* fw    = (const float*)d_in[1];
    const float* bw    = (const float*)d_in[2];
    const float* gc_w1 = (const float*)d_in[3];
    const float* gc_b1 = (const float*)d_in[4];
    const float* gc_w2 = (const float*)d_in[5];
    const float* gc_b2 = (const float*)d_in[6];
    const float* fc_w1 = (const float*)d_in[7];
    const float* fc_b1 = (const float*)d_in[8];
    const float* fc_w2 = (const float*)d_in[9];
    const float* fc_b2 = (const float*)d_in[10];
    float* out = (float*)d_out;

    char* ws = (char*)d_ws;
    u16*   Xb     = (u16*)(ws);                       // 8 MB
    u16*   H1     = (u16*)(ws + (8u  << 20));         // 8 MB
    u16*   W1t    = (u16*)(ws + (16u << 20));         // 2 MB
    u16*   W2t    = (u16*)(ws + (18u << 20));         // 2 MB
    float* pooled = (float*)(ws + (20u << 20));       // 1024 f
    float* zacc   = pooled + 1024;                    // 512 f
    u32*   cnt    = (u32*)(zacc + 512);               // 1 u32 (zeroed with pooled)

    k_prep<<<1024, 256, 0, stream>>>(x, gc_w1, gc_w2, Xb, W1t, W2t, pooled);
    k_gemmband<<<dim3(64, 16), 256, 0, stream>>>(Xb, W1t, gc_b1, fw, bw, H1, nullptr, 0);
    k_gemmband<<<dim3(64, 16), 256, 0, stream>>>(H1, W2t, gc_b2, fw, bw, nullptr, pooled, 1);
    k_fc<<<16, 512, 0, stream>>>(pooled, fc_w1, fc_b1, fc_w2, fc_b2, zacc, cnt, out);
}